// Round 10
// baseline (499.842 us; speedup 1.0000x reference)
//
#include <hip/hip_runtime.h>
#include <hip/hip_bf16.h>

typedef unsigned short u16;
typedef __attribute__((ext_vector_type(8))) short bf16x8;    // 8 bf16 in 4 VGPRs
typedef __attribute__((ext_vector_type(4))) float f32x4;

static __device__ __forceinline__ u16 f2bf(float f) {
    unsigned u = __float_as_uint(f);
    unsigned r = (u + 0x7fffu + ((u >> 16) & 1u)) >> 16;   // RNE
    return (u16)r;
}
static __device__ __forceinline__ float bf2f(u16 u) {
    return __uint_as_float(((unsigned)u) << 16);
}

static __device__ __forceinline__ void async_copy16(const void* gptr, void* lptr) {
    __builtin_amdgcn_global_load_lds(
        (const __attribute__((address_space(1))) void*)gptr,
        (__attribute__((address_space(3))) void*)lptr, 16, 0, 0);
}

// ---------------------------------------------------------------------------
// fp32 -> bf16 for all three inputs, grid-stride (4096 blocks x 8 iters).
// Unit = float4. hs: 4,194,304 units; Win: 3,145,728; Wout: 1,048,576.
// ---------------------------------------------------------------------------
__global__ __launch_bounds__(256)
void cvt_all(const float* __restrict__ a, const float* __restrict__ b,
             const float* __restrict__ c,
             u16* __restrict__ oa, u16* __restrict__ ob, u16* __restrict__ oc) {
#pragma unroll
    for (int it = 0; it < 8; it++) {
        long li = ((long)it << 20) + (long)blockIdx.x * 256 + threadIdx.x;
        const float* src; u16* dst; long u;
        if (li < 4194304)      { src = a; dst = oa; u = li; }
        else if (li < 7340032) { src = b; dst = ob; u = li - 4194304; }
        else                   { src = c; dst = oc; u = li - 7340032; }
        long i = u * 4;
        float4 f = *(const float4*)(src + i);
        u16 o[4] = { f2bf(f.x), f2bf(f.y), f2bf(f.z), f2bf(f.w) };
        *(uint2*)(dst + i) = *(const uint2*)o;
    }
}

// ---------------------------------------------------------------------------
// C[m,n] = sum_k A[m,k] * B[n,k]   (row-major, K contiguous — "BT" gemm)
//
// R6-VERBATIM schedule (measured best of R1/R5/R6/R7/R9: 178.0us, MfmaUtil
// 52%, SQ_LDS_BANK_CONFLICT 0). Only change: NON-TEMPORAL epilogue stores
// (output is streamed-once; FETCH showed ~122MB excess ~= WRITE_SIZE,
// suspected write-allocate/RFO — nt is a zero-schedule-risk fix+diagnostic).
//
// 256x256 tile, BK=64, 512 threads = 8 waves (2M x 4N), wave tile 128x64 as
// 8x4 frags of mfma_f32_16x16x32_bf16 (16-row fragment reads = measured ZERO
// bank conflicts; 32-row variants measured 1.9e7).
//
// 4 phases per K-tile, ONE s_barrier per phase. Phase = C-quadrant (Mq,Nq)
// x K=64 = 16 MFMA, split in two 8-MFMA halves by a COUNTED mid-wait:
//   body: [reads: B(4) | A-m01(4) | SB | A-m23(4)] [1 region staged]
//         [vmcnt @ph1(2)/ph4(4)] LGKM(4) SB 8xMFMA LGKM(0) SB 8xMFMA BAR
// Quadrant order (M0N0)(M0N1)(M1N1)(M1N0); B dbuf'd (ba/bb), A single set.
//
// Hazard calendar (audited): stages tile T: ph1 A0' ph2 B0' ph3 A1' ph4 B1'
// (tile T+1 -> other buf); vmcnt(4)@ph4 retires A0',B0' (read ph1' after
// BAR) — oldest 4 of 8; vmcnt(2)@ph1 retires A1,B1 (staged prev ph3/ph4;
// read ph2/ph3 after BAR); WAR: every stage target last read >= 3 phases
// (>= 3 barriers) earlier; queue never drained to 0 in-loop.
//
// LDS (2 dbufs x 32768 u16): A-Mq at Mq*8192 (256 row-slots x 64 u16),
// B-Nq at 16384+Nq*8192; 16B slot s = kc ^ (rowslot&7). Swizzle pre-applied
// on the GLOBAL source at staging (global_load_lds needs linear lane*16B
// dests); fragment reads un-swizzle with the same XOR.
// M,N mult of 256, K mult of 128, gridDim.x mult of 8.
// ---------------------------------------------------------------------------
template<bool BF16_OUT>
__global__ __launch_bounds__(512, 2)
void gemm_bt8(const u16* __restrict__ A, const u16* __restrict__ B,
              void* __restrict__ Cout, int M, int N, int K) {
    __shared__ __align__(16) u16 lds[65536];   // 128 KiB

    const int t    = threadIdx.x;              // 0..511
    const int lane = t & 63;
    const int wm   = (t >> 6) >> 2;            // 0..1
    const int wn   = (t >> 6) & 3;             // 0..3
    const int l15  = lane & 15;
    const int hi   = lane >> 4;                // 0..3
    const int l7   = lane & 7;

    // XCD-aware panel remap (bijective since gridDim.x % 8 == 0)
    const int id   = blockIdx.y * gridDim.x + blockIdx.x;
    const int cpx  = gridDim.x >> 3;
    const int bx   = (id & 7) * cpx + ((id >> 3) % cpx);
    const int by   = (id >> 3) / cpx;
    const long rowA = (long)by * 256;
    const long rowB = (long)bx * 256;

    // ---- staging sources (pre-swizzled global addresses, R1-verbatim) ----
    const int pl0 = t >> 3;                               // 0..63
    const int slotcol = ((t & 7) ^ (pl0 & 7)) * 8;
    const u16* Asrc[2][2]; const u16* Bsrc[2][2];
#pragma unroll
    for (int h = 0; h < 2; h++) {
        int gA0 = h * 64 + pl0;
        int gA1 = 128 + h * 64 + pl0;
        Asrc[h][0] = A + (rowA + gA0) * (long)K + slotcol;
        Asrc[h][1] = A + (rowA + gA1) * (long)K + slotcol;
        int nB0 = (pl0 >> 5) * 64 + h * 32 + (pl0 & 31);
        Bsrc[h][0] = B + (rowB + nB0) * (long)K + slotcol;
        Bsrc[h][1] = B + (rowB + nB0 + 128) * (long)K + slotcol;
    }
    const int t8 = t * 8;

    auto STAGE_A = [&](int bufo, int h, int kk) {
        u16* d = lds + bufo + h * 8192 + t8;
        async_copy16(Asrc[h][0] + kk, d);
        async_copy16(Asrc[h][1] + kk, d + 4096);
    };
    auto STAGE_B = [&](int bufo, int h, int kk) {
        u16* d = lds + bufo + 16384 + h * 8192 + t8;
        async_copy16(Bsrc[h][0] + kk, d);
        async_copy16(Bsrc[h][1] + kk, d + 4096);
    };

    // ---- fragment read offsets (u16 units, R1-verbatim) ----
    const int aBase = wm * 4096 + l15 * 64;
    const int bBase = 16384 + wn * 2048 + l15 * 64;
    const int sOff0 = (hi ^ l7) * 8;            // ks=0
    const int sOff1 = ((4 + hi) ^ l7) * 8;      // ks=1

    bf16x8 af[4][2], ba[2][2], bb[2][2];
    f32x4 acc[8][4] = {};

    auto LOAD_A2 = [&](int bufo, int Mq, int mb) {   // af[mb], af[mb+1]
        const u16* p = lds + bufo + Mq * 8192 + aBase + mb * 1024;
        af[mb][0]     = *(const bf16x8*)(p + sOff0);
        af[mb][1]     = *(const bf16x8*)(p + sOff1);
        af[mb + 1][0] = *(const bf16x8*)(p + 1024 + sOff0);
        af[mb + 1][1] = *(const bf16x8*)(p + 1024 + sOff1);
    };
    auto LOAD_B = [&](bf16x8 (&bg)[2][2], int bufo, int Nq) {
        const u16* p = lds + bufo + Nq * 8192 + bBase;
        bg[0][0] = *(const bf16x8*)(p + sOff0);
        bg[0][1] = *(const bf16x8*)(p + sOff1);
        bg[1][0] = *(const bf16x8*)(p + 1024 + sOff0);
        bg[1][1] = *(const bf16x8*)(p + 1024 + sOff1);
    };
    auto MFMA_H = [&](int Mq, int Nq, int mb, bf16x8 (&bg)[2][2]) {
        __builtin_amdgcn_s_setprio(1);
#pragma unroll
        for (int ks = 0; ks < 2; ks++)
#pragma unroll
            for (int m = mb; m < mb + 2; m++)
#pragma unroll
                for (int n = 0; n < 2; n++)
                    acc[Mq * 4 + m][Nq * 2 + n] =
                        __builtin_amdgcn_mfma_f32_16x16x32_bf16(
                            af[m][ks], bg[n][ks], acc[Mq * 4 + m][Nq * 2 + n],
                            0, 0, 0);
        __builtin_amdgcn_s_setprio(0);
    };

#define BAR()   __builtin_amdgcn_s_barrier()
#define SB()    __builtin_amdgcn_sched_barrier(0)
#define LGKM(n) do { asm volatile("s_waitcnt lgkmcnt(" #n ")" ::: "memory"); \
                     __builtin_amdgcn_sched_barrier(0); } while (0)
#define VM(n)   asm volatile("s_waitcnt vmcnt(" #n ")" ::: "memory")

    // one K-tile = 4 phases, 1 barrier each; reads from BC, stages -> BN
#define TILE(BC, BN, KK)                                                     \
    /*ph1 Q(M0N0)*/                                                          \
    LOAD_B(ba, BC, 0); LOAD_A2(BC, 0, 0); SB(); LOAD_A2(BC, 0, 2);           \
    STAGE_A(BN, 0, KK); VM(2);                                               \
    LGKM(4); MFMA_H(0, 0, 0, ba); LGKM(0); MFMA_H(0, 0, 2, ba); BAR();       \
    /*ph2 Q(M0N1)*/                                                          \
    LOAD_B(bb, BC, 1);                                                       \
    STAGE_B(BN, 0, KK);                                                      \
    LGKM(0); MFMA_H(0, 1, 0, bb); MFMA_H(0, 1, 2, bb); BAR();                \
    /*ph3 Q(M1N1)*/                                                          \
    LOAD_A2(BC, 1, 0); SB(); LOAD_A2(BC, 1, 2);                              \
    STAGE_A(BN, 1, KK);                                                      \
    LGKM(4); MFMA_H(1, 1, 0, bb); LGKM(0); MFMA_H(1, 1, 2, bb); BAR();       \
    /*ph4 Q(M1N0)*/                                                          \
    STAGE_B(BN, 1, KK); VM(4);                                               \
    MFMA_H(1, 0, 0, ba); MFMA_H(1, 0, 2, ba); BAR();

    // ---- prologue: stage ALL of tile0 -> buf0 ----
    STAGE_A(0, 0, 0);  STAGE_B(0, 0, 0);
    STAGE_A(0, 1, 0);  STAGE_B(0, 1, 0);
    asm volatile("s_waitcnt vmcnt(0)" ::: "memory");
    BAR();

    const int NT = K >> 6;                     // K/64 tiles, even
#pragma unroll 1
    for (int i = 0; i < NT; i += 2) {
        int k1 = (i + 1) << 6;                               // tile i+1 src
        int k2 = (i + 2 < NT) ? (i + 2) << 6 : 0;            // tail: junk,
        TILE(0, 32768, k1);                                  //  never read
        TILE(32768, 0, k2);
    }
    // drain in-flight LDS-targeted loads / reads before LDS dealloc
    asm volatile("s_waitcnt vmcnt(0) lgkmcnt(0)" ::: "memory");

#undef TILE
#undef VM
#undef LGKM
#undef SB
#undef BAR

    // ---- epilogue: 16x16 C/D layout col=lane&15, row=(lane>>4)*4+r ----
    // NON-TEMPORAL: output is written once and read once much later (BCx by
    // conv_fuse; out by the harness) — skip cache allocation on write.
    const long crowBase = rowA + wm * 128 + hi * 4;
    const long ccolBase = rowB + wn * 64 + l15;
#pragma unroll
    for (int mi = 0; mi < 8; mi++) {
#pragma unroll
        for (int nj = 0; nj < 4; nj++) {
            long base = (crowBase + mi * 16) * N + ccolBase + nj * 16;
#pragma unroll
            for (int r = 0; r < 4; r++) {
                float v = acc[mi][nj][r];
                long idx = base + (long)r * N;
                if (BF16_OUT)
                    __builtin_nontemporal_store(f2bf(v), (u16*)Cout + idx);
                else
                    __builtin_nontemporal_store(v, (float*)Cout + idx);
            }
        }
    }
}

// ---------------------------------------------------------------------------
// Fused Bx-product + depthwise causal conv(L=3) + C-gate, 4 rows/block.
// BCx: (8192, 6144) bf16 rows = [B(0:2048) | C(2048:4096) | x(4096:6144)]
// y[s,h] = C[s,h] * ( w[h,0]*Bx[s-2,h] + w[h,1]*Bx[s-1,h] + w[h,2]*Bx[s,h] )
// batch boundary: s resets every 4096 rows; 4096%4==0 so boundaries align
// to block starts — a tap row is valid iff it is in the block's batch.
// ---------------------------------------------------------------------------
union U16x8 { uint4 v; u16 u[8]; };

__global__ __launch_bounds__(256)
void conv_fuse(const u16* __restrict__ BCx, const float* __restrict__ cw,
               u16* __restrict__ y) {
    const int r0 = blockIdx.x * 4;         // 2048 blocks
    const int h0 = threadIdx.x * 8;        // 256*8 = 2048
    const int batch = r0 >> 12;

    U16x8 Bv[6], Xv[6], Cv[4];
#pragma unroll
    for (int ii = 0; ii < 6; ii++) {
        int g = r0 - 2 + ii;
        if (g >= 0 && (g >> 12) == batch) {
            const u16* rp = BCx + (long)g * 6144;
            Bv[ii].v = *(const uint4*)(rp + h0);
            Xv[ii].v = *(const uint4*)(rp + 4096 + h0);
        } else {
            Bv[ii].v = make_uint4(0, 0, 0, 0);
            Xv[ii].v = make_uint4(0, 0, 0, 0);
        }
    }
#pragma unroll
    for (int jj = 0; jj < 4; jj++)
        Cv[jj].v = *(const uint4*)(BCx + (long)(r0 + jj) * 6144 + 2048 + h0);

    float bx[6][8];
#pragma unroll
    for (int ii = 0; ii < 6; ii++)
#pragma unroll
        for (int i = 0; i < 8; i++)
            bx[ii][i] = bf2f(Bv[ii].u[i]) * bf2f(Xv[ii].u[i]);

    float w0[8], w1[8], w2[8];
#pragma unroll
    for (int i = 0; i < 8; i++) {
        int h = h0 + i;
        w0[i] = cw[h * 3];     // tap s-2
        w1[i] = cw[h * 3 + 1]; // tap s-1
        w2[i] = cw[h * 3 + 2]; // tap s
    }

#pragma unroll
    for (int jj = 0; jj < 4; jj++) {
        U16x8 o;
#pragma unroll
        for (int i = 0; i < 8; i++) {
            float v = w2[i] * bx[jj + 2][i] + w1[i] * bx[jj + 1][i]
                    + w0[i] * bx[jj][i];
            o.u[i] = f2bf(v * bf2f(Cv[jj].u[i]));
        }
        *(uint4*)(y + (long)(r0 + jj) * 2048 + h0) = o.v;
    }
}

// ---------------------------------------------------------------------------
extern "C" void kernel_launch(void* const* d_in, const int* in_sizes, int n_in,
                              void* d_out, int out_size, void* d_ws, size_t ws_size,
                              hipStream_t stream) {
    const float* hs   = (const float*)d_in[0];   // (2,4096,2048)
    const float* Win  = (const float*)d_in[1];   // (6144,2048)
    const float* cw   = (const float*)d_in[2];   // (2048,1,3)
    const float* Wout = (const float*)d_in[3];   // (2048,2048)
    float* out = (float*)d_out;                  // (2,4096,2048) fp32

    char* ws = (char*)d_ws;
    u16* hsb   = (u16*)(ws);                     //  33,554,432 B
    u16* Winb  = (u16*)(ws +  33554432);         //  25,165,824 B
    u16* Woutb = (u16*)(ws +  58720256);         //   8,388,608 B
    u16* bcx   = (u16*)(ws +  67108864);         // 100,663,296 B
    u16* yb    = (u16*)(ws + 167772160);         //  33,554,432 B  (end 201,326,592)

    cvt_all<<<4096, 256, 0, stream>>>(hs, Win, Wout, hsb, Winb, Woutb);

    // BCx = hs @ Win^T : M=8192, N=6144, K=2048  (grid 24x32 = 768 blocks)
    gemm_bt8<true ><<<dim3(24, 32), 512, 0, stream>>>(hsb, Winb, bcx, 8192, 6144, 2048);

    conv_fuse<<<2048, 256, 0, stream>>>(bcx, cw, yb);

    // out = y @ Wout^T : M=8192, N=2048, K=2048  (grid 8x32 = 256 blocks)
    gemm_bt8<false><<<dim3(8, 32), 512, 0, stream>>>(yb, Woutb, out, 8192, 2048, 2048);
}

// Round 11
// 442.112 us; speedup vs baseline: 1.1306x; 1.1306x over previous
//
#include <hip/hip_runtime.h>
#include <hip/hip_bf16.h>

typedef unsigned short u16;
typedef __attribute__((ext_vector_type(8))) short bf16x8;    // 8 bf16 in 4 VGPRs
typedef __attribute__((ext_vector_type(4))) float f32x4;

static __device__ __forceinline__ u16 f2bf(float f) {
    unsigned u = __float_as_uint(f);
    unsigned r = (u + 0x7fffu + ((u >> 16) & 1u)) >> 16;   // RNE
    return (u16)r;
}
static __device__ __forceinline__ float bf2f(u16 u) {
    return __uint_as_float(((unsigned)u) << 16);
}

static __device__ __forceinline__ void async_copy16(const void* gptr, void* lptr) {
    __builtin_amdgcn_global_load_lds(
        (const __attribute__((address_space(1))) void*)gptr,
        (__attribute__((address_space(3))) void*)lptr, 16, 0, 0);
}

// ---------------------------------------------------------------------------
// fp32 -> bf16 for all three inputs, grid-stride (4096 blocks x 8 iters).
// Unit = float4. hs: 4,194,304 units; Win: 3,145,728; Wout: 1,048,576.
// ---------------------------------------------------------------------------
__global__ __launch_bounds__(256)
void cvt_all(const float* __restrict__ a, const float* __restrict__ b,
             const float* __restrict__ c,
             u16* __restrict__ oa, u16* __restrict__ ob, u16* __restrict__ oc) {
#pragma unroll
    for (int it = 0; it < 8; it++) {
        long li = ((long)it << 20) + (long)blockIdx.x * 256 + threadIdx.x;
        const float* src; u16* dst; long u;
        if (li < 4194304)      { src = a; dst = oa; u = li; }
        else if (li < 7340032) { src = b; dst = ob; u = li - 4194304; }
        else                   { src = c; dst = oc; u = li - 7340032; }
        long i = u * 4;
        float4 f = *(const float4*)(src + i);
        u16 o[4] = { f2bf(f.x), f2bf(f.y), f2bf(f.z), f2bf(f.w) };
        *(uint2*)(dst + i) = *(const uint2*)o;
    }
}

// ---------------------------------------------------------------------------
// C[m,n] = sum_k A[m,k] * B[n,k]   (row-major, K contiguous — "BT" gemm)
//
// R6-VERBATIM (measured best across R1/R5/R6/R7/R9/R10: 178.0us, 1160 TF,
// MfmaUtil 52%, SQ_LDS_BANK_CONFLICT 0, plain epilogue stores — R10 proved
// nt stores double WRITE_SIZE via partial-line HBM writes; reverted).
//
// 256x256 tile, BK=64, 512 threads = 8 waves (2M x 4N), wave tile 128x64 as
// 8x4 frags of mfma_f32_16x16x32_bf16 (16-row fragment reads = measured ZERO
// bank conflicts; 32-row variants measured 1.9e7).
//
// 4 phases per K-tile, ONE s_barrier per phase. Phase = C-quadrant (Mq,Nq)
// x K=64 = 16 MFMA, split in two 8-MFMA halves by a COUNTED mid-wait:
//   body: [reads: B(4) | A-m01(4) | SB | A-m23(4)] [1 region staged]
//         [vmcnt @ph1(2)/ph4(4)] LGKM(4) SB 8xMFMA LGKM(0) SB 8xMFMA BAR
// Quadrant order (M0N0)(M0N1)(M1N1)(M1N0); B dbuf'd (ba/bb), A single set.
//
// Hazard calendar (audited): stages tile T: ph1 A0' ph2 B0' ph3 A1' ph4 B1'
// (tile T+1 -> other buf); vmcnt(4)@ph4 retires A0',B0' (read ph1' after
// BAR) — oldest 4 of 8; vmcnt(2)@ph1 retires A1,B1 (staged prev ph3/ph4;
// read ph2/ph3 after BAR); WAR: every stage target last read >= 3 phases
// (>= 3 barriers) earlier; queue never drained to 0 in-loop.
//
// LDS (2 dbufs x 32768 u16): A-Mq at Mq*8192 (256 row-slots x 64 u16),
// B-Nq at 16384+Nq*8192; 16B slot s = kc ^ (rowslot&7). Swizzle pre-applied
// on the GLOBAL source at staging (global_load_lds needs linear lane*16B
// dests); fragment reads un-swizzle with the same XOR.
// M,N mult of 256, K mult of 128, gridDim.x mult of 8.
// ---------------------------------------------------------------------------
template<bool BF16_OUT>
__global__ __launch_bounds__(512, 2)
void gemm_bt8(const u16* __restrict__ A, const u16* __restrict__ B,
              void* __restrict__ Cout, int M, int N, int K) {
    __shared__ __align__(16) u16 lds[65536];   // 128 KiB

    const int t    = threadIdx.x;              // 0..511
    const int lane = t & 63;
    const int wm   = (t >> 6) >> 2;            // 0..1
    const int wn   = (t >> 6) & 3;             // 0..3
    const int l15  = lane & 15;
    const int hi   = lane >> 4;                // 0..3
    const int l7   = lane & 7;

    // XCD-aware panel remap (bijective since gridDim.x % 8 == 0)
    const int id   = blockIdx.y * gridDim.x + blockIdx.x;
    const int cpx  = gridDim.x >> 3;
    const int bx   = (id & 7) * cpx + ((id >> 3) % cpx);
    const int by   = (id >> 3) / cpx;
    const long rowA = (long)by * 256;
    const long rowB = (long)bx * 256;

    // ---- staging sources (pre-swizzled global addresses, R1-verbatim) ----
    const int pl0 = t >> 3;                               // 0..63
    const int slotcol = ((t & 7) ^ (pl0 & 7)) * 8;
    const u16* Asrc[2][2]; const u16* Bsrc[2][2];
#pragma unroll
    for (int h = 0; h < 2; h++) {
        int gA0 = h * 64 + pl0;
        int gA1 = 128 + h * 64 + pl0;
        Asrc[h][0] = A + (rowA + gA0) * (long)K + slotcol;
        Asrc[h][1] = A + (rowA + gA1) * (long)K + slotcol;
        int nB0 = (pl0 >> 5) * 64 + h * 32 + (pl0 & 31);
        Bsrc[h][0] = B + (rowB + nB0) * (long)K + slotcol;
        Bsrc[h][1] = B + (rowB + nB0 + 128) * (long)K + slotcol;
    }
    const int t8 = t * 8;

    auto STAGE_A = [&](int bufo, int h, int kk) {
        u16* d = lds + bufo + h * 8192 + t8;
        async_copy16(Asrc[h][0] + kk, d);
        async_copy16(Asrc[h][1] + kk, d + 4096);
    };
    auto STAGE_B = [&](int bufo, int h, int kk) {
        u16* d = lds + bufo + 16384 + h * 8192 + t8;
        async_copy16(Bsrc[h][0] + kk, d);
        async_copy16(Bsrc[h][1] + kk, d + 4096);
    };

    // ---- fragment read offsets (u16 units, R1-verbatim) ----
    const int aBase = wm * 4096 + l15 * 64;
    const int bBase = 16384 + wn * 2048 + l15 * 64;
    const int sOff0 = (hi ^ l7) * 8;            // ks=0
    const int sOff1 = ((4 + hi) ^ l7) * 8;      // ks=1

    bf16x8 af[4][2], ba[2][2], bb[2][2];
    f32x4 acc[8][4] = {};

    auto LOAD_A2 = [&](int bufo, int Mq, int mb) {   // af[mb], af[mb+1]
        const u16* p = lds + bufo + Mq * 8192 + aBase + mb * 1024;
        af[mb][0]     = *(const bf16x8*)(p + sOff0);
        af[mb][1]     = *(const bf16x8*)(p + sOff1);
        af[mb + 1][0] = *(const bf16x8*)(p + 1024 + sOff0);
        af[mb + 1][1] = *(const bf16x8*)(p + 1024 + sOff1);
    };
    auto LOAD_B = [&](bf16x8 (&bg)[2][2], int bufo, int Nq) {
        const u16* p = lds + bufo + Nq * 8192 + bBase;
        bg[0][0] = *(const bf16x8*)(p + sOff0);
        bg[0][1] = *(const bf16x8*)(p + sOff1);
        bg[1][0] = *(const bf16x8*)(p + 1024 + sOff0);
        bg[1][1] = *(const bf16x8*)(p + 1024 + sOff1);
    };
    auto MFMA_H = [&](int Mq, int Nq, int mb, bf16x8 (&bg)[2][2]) {
        __builtin_amdgcn_s_setprio(1);
#pragma unroll
        for (int ks = 0; ks < 2; ks++)
#pragma unroll
            for (int m = mb; m < mb + 2; m++)
#pragma unroll
                for (int n = 0; n < 2; n++)
                    acc[Mq * 4 + m][Nq * 2 + n] =
                        __builtin_amdgcn_mfma_f32_16x16x32_bf16(
                            af[m][ks], bg[n][ks], acc[Mq * 4 + m][Nq * 2 + n],
                            0, 0, 0);
        __builtin_amdgcn_s_setprio(0);
    };

#define BAR()   __builtin_amdgcn_s_barrier()
#define SB()    __builtin_amdgcn_sched_barrier(0)
#define LGKM(n) do { asm volatile("s_waitcnt lgkmcnt(" #n ")" ::: "memory"); \
                     __builtin_amdgcn_sched_barrier(0); } while (0)
#define VM(n)   asm volatile("s_waitcnt vmcnt(" #n ")" ::: "memory")

    // one K-tile = 4 phases, 1 barrier each; reads from BC, stages -> BN
#define TILE(BC, BN, KK)                                                     \
    /*ph1 Q(M0N0)*/                                                          \
    LOAD_B(ba, BC, 0); LOAD_A2(BC, 0, 0); SB(); LOAD_A2(BC, 0, 2);           \
    STAGE_A(BN, 0, KK); VM(2);                                               \
    LGKM(4); MFMA_H(0, 0, 0, ba); LGKM(0); MFMA_H(0, 0, 2, ba); BAR();       \
    /*ph2 Q(M0N1)*/                                                          \
    LOAD_B(bb, BC, 1);                                                       \
    STAGE_B(BN, 0, KK);                                                      \
    LGKM(0); MFMA_H(0, 1, 0, bb); MFMA_H(0, 1, 2, bb); BAR();                \
    /*ph3 Q(M1N1)*/                                                          \
    LOAD_A2(BC, 1, 0); SB(); LOAD_A2(BC, 1, 2);                              \
    STAGE_A(BN, 1, KK);                                                      \
    LGKM(4); MFMA_H(1, 1, 0, bb); LGKM(0); MFMA_H(1, 1, 2, bb); BAR();       \
    /*ph4 Q(M1N0)*/                                                          \
    STAGE_B(BN, 1, KK); VM(4);                                               \
    MFMA_H(1, 0, 0, ba); MFMA_H(1, 0, 2, ba); BAR();

    // ---- prologue: stage ALL of tile0 -> buf0 ----
    STAGE_A(0, 0, 0);  STAGE_B(0, 0, 0);
    STAGE_A(0, 1, 0);  STAGE_B(0, 1, 0);
    asm volatile("s_waitcnt vmcnt(0)" ::: "memory");
    BAR();

    const int NT = K >> 6;                     // K/64 tiles, even
#pragma unroll 1
    for (int i = 0; i < NT; i += 2) {
        int k1 = (i + 1) << 6;                               // tile i+1 src
        int k2 = (i + 2 < NT) ? (i + 2) << 6 : 0;            // tail: junk,
        TILE(0, 32768, k1);                                  //  never read
        TILE(32768, 0, k2);
    }
    // drain in-flight LDS-targeted loads / reads before LDS dealloc
    asm volatile("s_waitcnt vmcnt(0) lgkmcnt(0)" ::: "memory");

#undef TILE
#undef VM
#undef LGKM
#undef SB
#undef BAR

    // ---- epilogue: 16x16 C/D layout col=lane&15, row=(lane>>4)*4+r ----
    const long crowBase = rowA + wm * 128 + hi * 4;
    const long ccolBase = rowB + wn * 64 + l15;
#pragma unroll
    for (int mi = 0; mi < 8; mi++) {
#pragma unroll
        for (int nj = 0; nj < 4; nj++) {
            long base = (crowBase + mi * 16) * N + ccolBase + nj * 16;
#pragma unroll
            for (int r = 0; r < 4; r++) {
                float v = acc[mi][nj][r];
                long idx = base + (long)r * N;
                if (BF16_OUT) ((u16*)Cout)[idx] = f2bf(v);
                else          ((float*)Cout)[idx] = v;
            }
        }
    }
}

// ---------------------------------------------------------------------------
// Fused Bx-product + depthwise causal conv(L=3) + C-gate, 4 rows/block.
// BCx: (8192, 6144) bf16 rows = [B(0:2048) | C(2048:4096) | x(4096:6144)]
// y[s,h] = C[s,h] * ( w[h,0]*Bx[s-2,h] + w[h,1]*Bx[s-1,h] + w[h,2]*Bx[s,h] )
// batch boundary: s resets every 4096 rows; 4096%4==0 so boundaries align
// to block starts — a tap row is valid iff it is in the block's batch.
// ---------------------------------------------------------------------------
union U16x8 { uint4 v; u16 u[8]; };

__global__ __launch_bounds__(256)
void conv_fuse(const u16* __restrict__ BCx, const float* __restrict__ cw,
               u16* __restrict__ y) {
    const int r0 = blockIdx.x * 4;         // 2048 blocks
    const int h0 = threadIdx.x * 8;        // 256*8 = 2048
    const int batch = r0 >> 12;

    U16x8 Bv[6], Xv[6], Cv[4];
#pragma unroll
    for (int ii = 0; ii < 6; ii++) {
        int g = r0 - 2 + ii;
        if (g >= 0 && (g >> 12) == batch) {
            const u16* rp = BCx + (long)g * 6144;
            Bv[ii].v = *(const uint4*)(rp + h0);
            Xv[ii].v = *(const uint4*)(rp + 4096 + h0);
        } else {
            Bv[ii].v = make_uint4(0, 0, 0, 0);
            Xv[ii].v = make_uint4(0, 0, 0, 0);
        }
    }
#pragma unroll
    for (int jj = 0; jj < 4; jj++)
        Cv[jj].v = *(const uint4*)(BCx + (long)(r0 + jj) * 6144 + 2048 + h0);

    float bx[6][8];
#pragma unroll
    for (int ii = 0; ii < 6; ii++)
#pragma unroll
        for (int i = 0; i < 8; i++)
            bx[ii][i] = bf2f(Bv[ii].u[i]) * bf2f(Xv[ii].u[i]);

    float w0[8], w1[8], w2[8];
#pragma unroll
    for (int i = 0; i < 8; i++) {
        int h = h0 + i;
        w0[i] = cw[h * 3];     // tap s-2
        w1[i] = cw[h * 3 + 1]; // tap s-1
        w2[i] = cw[h * 3 + 2]; // tap s
    }

#pragma unroll
    for (int jj = 0; jj < 4; jj++) {
        U16x8 o;
#pragma unroll
        for (int i = 0; i < 8; i++) {
            float v = w2[i] * bx[jj + 2][i] + w1[i] * bx[jj + 1][i]
                    + w0[i] * bx[jj][i];
            o.u[i] = f2bf(v * bf2f(Cv[jj].u[i]));
        }
        *(uint4*)(y + (long)(r0 + jj) * 2048 + h0) = o.v;
    }
}

// ---------------------------------------------------------------------------
extern "C" void kernel_launch(void* const* d_in, const int* in_sizes, int n_in,
                              void* d_out, int out_size, void* d_ws, size_t ws_size,
                              hipStream_t stream) {
    const float* hs   = (const float*)d_in[0];   // (2,4096,2048)
    const float* Win  = (const float*)d_in[1];   // (6144,2048)
    const float* cw   = (const float*)d_in[2];   // (2048,1,3)
    const float* Wout = (const float*)d_in[3];   // (2048,2048)
    float* out = (float*)d_out;                  // (2,4096,2048) fp32

    char* ws = (char*)d_ws;
    u16* hsb   = (u16*)(ws);                     //  33,554,432 B
    u16* Winb  = (u16*)(ws +  33554432);         //  25,165,824 B
    u16* Woutb = (u16*)(ws +  58720256);         //   8,388,608 B
    u16* bcx   = (u16*)(ws +  67108864);         // 100,663,296 B
    u16* yb    = (u16*)(ws + 167772160);         //  33,554,432 B  (end 201,326,592)

    cvt_all<<<4096, 256, 0, stream>>>(hs, Win, Wout, hsb, Winb, Woutb);

    // BCx = hs @ Win^T : M=8192, N=6144, K=2048  (grid 24x32 = 768 blocks)
    gemm_bt8<true ><<<dim3(24, 32), 512, 0, stream>>>(hsb, Winb, bcx, 8192, 6144, 2048);

    conv_fuse<<<2048, 256, 0, stream>>>(bcx, cw, yb);

    // out = y @ Wout^T : M=8192, N=2048, K=2048  (grid 8x32 = 256 blocks)
    gemm_bt8<false><<<dim3(8, 32), 512, 0, stream>>>(yb, Woutb, out, 8192, 2048, 2048);
}

// Round 12
// 413.164 us; speedup vs baseline: 1.2098x; 1.0701x over previous
//
#include <hip/hip_runtime.h>
#include <hip/hip_bf16.h>

typedef unsigned short u16;
typedef __attribute__((ext_vector_type(8))) short bf16x8;    // 8 bf16 in 4 VGPRs
typedef __attribute__((ext_vector_type(4))) float f32x4;

static __device__ __forceinline__ u16 f2bf(float f) {
    unsigned u = __float_as_uint(f);
    unsigned r = (u + 0x7fffu + ((u >> 16) & 1u)) >> 16;   // RNE
    return (u16)r;
}
static __device__ __forceinline__ float bf2f(u16 u) {
    return __uint_as_float(((unsigned)u) << 16);
}

static __device__ __forceinline__ void async_copy16(const void* gptr, void* lptr) {
    __builtin_amdgcn_global_load_lds(
        (const __attribute__((address_space(1))) void*)gptr,
        (__attribute__((address_space(3))) void*)lptr, 16, 0, 0);
}

// ---------------------------------------------------------------------------
// fp32 -> bf16 for all three inputs, grid-stride (4096 blocks x 8 iters).
// Unit = float4. hs: 4,194,304 units; Win: 3,145,728; Wout: 1,048,576.
// ---------------------------------------------------------------------------
__global__ __launch_bounds__(256)
void cvt_all(const float* __restrict__ a, const float* __restrict__ b,
             const float* __restrict__ c,
             u16* __restrict__ oa, u16* __restrict__ ob, u16* __restrict__ oc) {
#pragma unroll
    for (int it = 0; it < 8; it++) {
        long li = ((long)it << 20) + (long)blockIdx.x * 256 + threadIdx.x;
        const float* src; u16* dst; long u;
        if (li < 4194304)      { src = a; dst = oa; u = li; }
        else if (li < 7340032) { src = b; dst = ob; u = li - 4194304; }
        else                   { src = c; dst = oc; u = li - 7340032; }
        long i = u * 4;
        float4 f = *(const float4*)(src + i);
        u16 o[4] = { f2bf(f.x), f2bf(f.y), f2bf(f.z), f2bf(f.w) };
        *(uint2*)(dst + i) = *(const uint2*)o;
    }
}

// ---------------------------------------------------------------------------
// C[m,n] = sum_k A[m,k] * B[n,k]   (row-major, K contiguous — "BT" gemm)
//
// K-loop/LDS/schedule = R6-VERBATIM (measured best: ~180us gemm1, MfmaUtil
// 52%, SQ_LDS_BANK_CONFLICT 0). R12 changes are OUTSIDE the K-loop:
//
// FUSED mode (gemm1): 24 col-panels remapped —
//   panels bx<16: "Bx panels". Region N0 staged from Win rows bx*128+[0,128)
//     (= B weights), region N1 from 4096+bx*128+[0,128) (= x weights). Slot
//     algebra: region slot s holds Win row segBase+bx*128+s, so fragment
//     (wn,Nq,n,l15) = h = bx*128+wn*32+n*16+l15, SAME h for Nq=0/1. The
//     epilogue forms Bx = acc[mi][n]*acc[mi][n+2] in-register and writes one
//     bf16 Bx buffer (stride 2048) — B and x never hit memory.
//   panels bx>=16: "C panels", standard mapping at Win rows 2048+(bx-16)*256,
//     written to a separate C buffer (stride 2048).
// This halves gemm1's output traffic (100->67MB) and removes conv's B*x
// re-read+multiply entirely.
//
// Tail fix: final junk-stage re-stages the CURRENT (L2-hot) K-tile instead
// of k=0 (removes ~50MB of cold junk fetches across the grid).
//
// 256x256 tile, BK=64, 512 threads = 8 waves (2M x 4N), wave tile 128x64 as
// 8x4 frags of mfma_f32_16x16x32_bf16 (16-row fragment reads = measured ZERO
// bank conflicts; 32-row variants measured 1.9e7).
// 4 phases per K-tile, ONE s_barrier per phase; counted vmcnt (never 0
// in-loop); stages ph1 A0' ph2 B0' ph3 A1' ph4 B1' -> other buf; vmcnt(4)@ph4
// retires A0',B0'; vmcnt(2)@ph1 retires A1,B1; WAR >= 3 barriers. LDS
// (2 dbufs x 32768 u16): A-Mq at Mq*8192, B-Nq at 16384+Nq*8192; 16B slot
// s = kc ^ (rowslot&7), swizzle pre-applied on the GLOBAL source.
// M,N mult of 256, K mult of 128, gridDim.x mult of 8.
// ---------------------------------------------------------------------------
template<bool FUSED>
__global__ __launch_bounds__(512, 2)
void gemm_bt8(const u16* __restrict__ A, const u16* __restrict__ B,
              u16* __restrict__ oBx, u16* __restrict__ oC,
              float* __restrict__ oF, int M, int N, int K) {
    __shared__ __align__(16) u16 lds[65536];   // 128 KiB

    const int t    = threadIdx.x;              // 0..511
    const int lane = t & 63;
    const int wm   = (t >> 6) >> 2;            // 0..1
    const int wn   = (t >> 6) & 3;             // 0..3
    const int l15  = lane & 15;
    const int hi   = lane >> 4;                // 0..3
    const int l7   = lane & 7;

    // XCD-aware panel remap (bijective since gridDim.x % 8 == 0)
    const int id   = blockIdx.y * gridDim.x + blockIdx.x;
    const int cpx  = gridDim.x >> 3;
    const int bx   = (id & 7) * cpx + ((id >> 3) % cpx);
    const int by   = (id >> 3) / cpx;
    const long rowA = (long)by * 256;

    // ---- staging sources (pre-swizzled global addresses) ----
    const int pl0 = t >> 3;                               // 0..63
    const int slotcol = ((t & 7) ^ (pl0 & 7)) * 8;
    const u16* Asrc[2][2]; const u16* Bsrc[2][2];
#pragma unroll
    for (int h = 0; h < 2; h++) {
        int gA0 = h * 64 + pl0;
        int gA1 = 128 + h * 64 + pl0;
        Asrc[h][0] = A + (rowA + gA0) * (long)K + slotcol;
        Asrc[h][1] = A + (rowA + gA1) * (long)K + slotcol;
    }
    if (FUSED && bx < 16) {
        // Bx panel: region 0 <- B rows (Win [0,2048)), region 1 <- x rows
        const long rB = (long)bx * 128 + pl0;
        Bsrc[0][0] = B + rB * (long)K + slotcol;
        Bsrc[0][1] = Bsrc[0][0] + 64 * (long)K;
        Bsrc[1][0] = B + (4096 + rB) * (long)K + slotcol;
        Bsrc[1][1] = Bsrc[1][0] + 64 * (long)K;
    } else {
        const long rowB = FUSED ? (2048 + (long)(bx - 16) * 256)
                                : (long)bx * 256;
#pragma unroll
        for (int h = 0; h < 2; h++) {
            int nB0 = (pl0 >> 5) * 64 + h * 32 + (pl0 & 31);
            Bsrc[h][0] = B + (rowB + nB0) * (long)K + slotcol;
            Bsrc[h][1] = Bsrc[h][0] + 128 * (long)K;
        }
    }
    const int t8 = t * 8;

    auto STAGE_A = [&](int bufo, int h, int kk) {
        u16* d = lds + bufo + h * 8192 + t8;
        async_copy16(Asrc[h][0] + kk, d);
        async_copy16(Asrc[h][1] + kk, d + 4096);
    };
    auto STAGE_B = [&](int bufo, int h, int kk) {
        u16* d = lds + bufo + 16384 + h * 8192 + t8;
        async_copy16(Bsrc[h][0] + kk, d);
        async_copy16(Bsrc[h][1] + kk, d + 4096);
    };

    // ---- fragment read offsets (u16 units) ----
    const int aBase = wm * 4096 + l15 * 64;
    const int bBase = 16384 + wn * 2048 + l15 * 64;
    const int sOff0 = (hi ^ l7) * 8;            // ks=0
    const int sOff1 = ((4 + hi) ^ l7) * 8;      // ks=1

    bf16x8 af[4][2], ba[2][2], bb[2][2];
    f32x4 acc[8][4] = {};

    auto LOAD_A2 = [&](int bufo, int Mq, int mb) {   // af[mb], af[mb+1]
        const u16* p = lds + bufo + Mq * 8192 + aBase + mb * 1024;
        af[mb][0]     = *(const bf16x8*)(p + sOff0);
        af[mb][1]     = *(const bf16x8*)(p + sOff1);
        af[mb + 1][0] = *(const bf16x8*)(p + 1024 + sOff0);
        af[mb + 1][1] = *(const bf16x8*)(p + 1024 + sOff1);
    };
    auto LOAD_B = [&](bf16x8 (&bg)[2][2], int bufo, int Nq) {
        const u16* p = lds + bufo + Nq * 8192 + bBase;
        bg[0][0] = *(const bf16x8*)(p + sOff0);
        bg[0][1] = *(const bf16x8*)(p + sOff1);
        bg[1][0] = *(const bf16x8*)(p + 1024 + sOff0);
        bg[1][1] = *(const bf16x8*)(p + 1024 + sOff1);
    };
    auto MFMA_H = [&](int Mq, int Nq, int mb, bf16x8 (&bg)[2][2]) {
        __builtin_amdgcn_s_setprio(1);
#pragma unroll
        for (int ks = 0; ks < 2; ks++)
#pragma unroll
            for (int m = mb; m < mb + 2; m++)
#pragma unroll
                for (int n = 0; n < 2; n++)
                    acc[Mq * 4 + m][Nq * 2 + n] =
                        __builtin_amdgcn_mfma_f32_16x16x32_bf16(
                            af[m][ks], bg[n][ks], acc[Mq * 4 + m][Nq * 2 + n],
                            0, 0, 0);
        __builtin_amdgcn_s_setprio(0);
    };

#define BAR()   __builtin_amdgcn_s_barrier()
#define SB()    __builtin_amdgcn_sched_barrier(0)
#define LGKM(n) do { asm volatile("s_waitcnt lgkmcnt(" #n ")" ::: "memory"); \
                     __builtin_amdgcn_sched_barrier(0); } while (0)
#define VM(n)   asm volatile("s_waitcnt vmcnt(" #n ")" ::: "memory")

    // one K-tile = 4 phases, 1 barrier each; reads from BC, stages -> BN
#define TILE(BC, BN, KK)                                                     \
    /*ph1 Q(M0N0)*/                                                          \
    LOAD_B(ba, BC, 0); LOAD_A2(BC, 0, 0); SB(); LOAD_A2(BC, 0, 2);           \
    STAGE_A(BN, 0, KK); VM(2);                                               \
    LGKM(4); MFMA_H(0, 0, 0, ba); LGKM(0); MFMA_H(0, 0, 2, ba); BAR();       \
    /*ph2 Q(M0N1)*/                                                          \
    LOAD_B(bb, BC, 1);                                                       \
    STAGE_B(BN, 0, KK);                                                      \
    LGKM(0); MFMA_H(0, 1, 0, bb); MFMA_H(0, 1, 2, bb); BAR();                \
    /*ph3 Q(M1N1)*/                                                          \
    LOAD_A2(BC, 1, 0); SB(); LOAD_A2(BC, 1, 2);                              \
    STAGE_A(BN, 1, KK);                                                      \
    LGKM(4); MFMA_H(1, 1, 0, bb); LGKM(0); MFMA_H(1, 1, 2, bb); BAR();       \
    /*ph4 Q(M1N0)*/                                                          \
    STAGE_B(BN, 1, KK); VM(4);                                               \
    MFMA_H(1, 0, 0, ba); MFMA_H(1, 0, 2, ba); BAR();

    // ---- prologue: stage ALL of tile0 -> buf0 ----
    STAGE_A(0, 0, 0);  STAGE_B(0, 0, 0);
    STAGE_A(0, 1, 0);  STAGE_B(0, 1, 0);
    asm volatile("s_waitcnt vmcnt(0)" ::: "memory");
    BAR();

    const int NT = K >> 6;                     // K/64 tiles, even
#pragma unroll 1
    for (int i = 0; i < NT; i += 2) {
        int k1 = (i + 1) << 6;                               // tile i+1 src
        int k2 = (i + 2 < NT) ? (i + 2) << 6 : k1;           // tail: junk but
        TILE(0, 32768, k1);                                  //  L2-HOT, never
        TILE(32768, 0, k2);                                  //  read
    }
    // drain in-flight LDS-targeted loads / reads before LDS dealloc
    asm volatile("s_waitcnt vmcnt(0) lgkmcnt(0)" ::: "memory");

#undef TILE
#undef VM
#undef LGKM
#undef SB
#undef BAR

    // ---- epilogue: 16x16 C/D layout col=lane&15, row=(lane>>4)*4+r ----
    const long rBase = rowA + wm * 128 + hi * 4;
    if (FUSED && bx < 16) {
        // Bx panel: acc[mi][n] = B, acc[mi][n+2] = x at the SAME h
        const long hBase = (long)bx * 128 + wn * 32 + l15;
#pragma unroll
        for (int mi = 0; mi < 8; mi++) {
#pragma unroll
            for (int n = 0; n < 2; n++) {
                long col = hBase + n * 16;
#pragma unroll
                for (int r = 0; r < 4; r++) {
                    long row = rBase + mi * 16 + r;
                    float v = acc[mi][n][r] * acc[mi][n + 2][r];
                    oBx[row * 2048 + col] = f2bf(v);
                }
            }
        }
    } else if (FUSED) {
        // C panel
        const long colBase = (long)(bx - 16) * 256 + wn * 64 + l15;
#pragma unroll
        for (int mi = 0; mi < 8; mi++)
#pragma unroll
            for (int nj = 0; nj < 4; nj++)
#pragma unroll
                for (int r = 0; r < 4; r++) {
                    long row = rBase + mi * 16 + r;
                    oC[row * 2048 + colBase + nj * 16] = f2bf(acc[mi][nj][r]);
                }
    } else {
        const long colBase = (long)bx * 256 + wn * 64 + l15;
#pragma unroll
        for (int mi = 0; mi < 8; mi++)
#pragma unroll
            for (int nj = 0; nj < 4; nj++)
#pragma unroll
                for (int r = 0; r < 4; r++) {
                    long row = rBase + mi * 16 + r;
                    oF[row * (long)N + colBase + nj * 16] = acc[mi][nj][r];
                }
    }
}

// ---------------------------------------------------------------------------
// Depthwise causal conv(L=3) + C-gate on precomputed Bx, 8 rows/block.
// Bx,Cc: (8192, 2048) bf16.  y[s,h] = C[s,h] * (w0*Bx[s-2,h] + w1*Bx[s-1,h]
// + w2*Bx[s,h]).  Batch boundary: s resets every 4096 rows; 4096%8==0 so
// boundaries align to block starts.
// ---------------------------------------------------------------------------
union U16x8 { uint4 v; u16 u[8]; };

__global__ __launch_bounds__(256)
void conv_fuse(const u16* __restrict__ Bx, const u16* __restrict__ Cc,
               const float* __restrict__ cw, u16* __restrict__ y) {
    const int r0 = blockIdx.x * 8;         // 1024 blocks
    const int h0 = threadIdx.x * 8;        // 256*8 = 2048
    const int batch = r0 >> 12;

    U16x8 P[10];
#pragma unroll
    for (int ii = 0; ii < 10; ii++) {
        int g = r0 - 2 + ii;
        if (g >= 0 && (g >> 12) == batch)
            P[ii].v = *(const uint4*)(Bx + (long)g * 2048 + h0);
        else
            P[ii].v = make_uint4(0, 0, 0, 0);
    }
    float bx[10][8];
#pragma unroll
    for (int ii = 0; ii < 10; ii++)
#pragma unroll
        for (int i = 0; i < 8; i++)
            bx[ii][i] = bf2f(P[ii].u[i]);

    float w0[8], w1[8], w2[8];
#pragma unroll
    for (int i = 0; i < 8; i++) {
        int h = h0 + i;
        w0[i] = cw[h * 3];     // tap s-2
        w1[i] = cw[h * 3 + 1]; // tap s-1
        w2[i] = cw[h * 3 + 2]; // tap s
    }

#pragma unroll
    for (int jj = 0; jj < 8; jj++) {
        U16x8 Cv, o;
        Cv.v = *(const uint4*)(Cc + (long)(r0 + jj) * 2048 + h0);
#pragma unroll
        for (int i = 0; i < 8; i++) {
            float v = w2[i] * bx[jj + 2][i] + w1[i] * bx[jj + 1][i]
                    + w0[i] * bx[jj][i];
            o.u[i] = f2bf(v * bf2f(Cv.u[i]));
        }
        *(uint4*)(y + (long)(r0 + jj) * 2048 + h0) = o.v;
    }
}

// ---------------------------------------------------------------------------
extern "C" void kernel_launch(void* const* d_in, const int* in_sizes, int n_in,
                              void* d_out, int out_size, void* d_ws, size_t ws_size,
                              hipStream_t stream) {
    const float* hs   = (const float*)d_in[0];   // (2,4096,2048)
    const float* Win  = (const float*)d_in[1];   // (6144,2048)
    const float* cw   = (const float*)d_in[2];   // (2048,1,3)
    const float* Wout = (const float*)d_in[3];   // (2048,2048)
    float* out = (float*)d_out;                  // (2,4096,2048) fp32

    char* ws = (char*)d_ws;
    u16* hsb   = (u16*)(ws);                     //  33,554,432 B
    u16* Winb  = (u16*)(ws +  33554432);         //  25,165,824 B
    u16* Woutb = (u16*)(ws +  58720256);         //   8,388,608 B
    u16* bxb   = (u16*)(ws +  67108864);         //  33,554,432 B
    u16* cb    = (u16*)(ws + 100663296);         //  33,554,432 B
    u16* yb    = (u16*)(ws + 134217728);         //  33,554,432 B  (end 167,772,160)

    cvt_all<<<4096, 256, 0, stream>>>(hs, Win, Wout, hsb, Winb, Woutb);

    // fused gemm1: Bx = (hs@WinB^T)*(hs@WinX^T), C = hs@WinC^T
    gemm_bt8<true ><<<dim3(24, 32), 512, 0, stream>>>(
        hsb, Winb, bxb, cb, nullptr, 8192, 2048, 2048);

    conv_fuse<<<1024, 256, 0, stream>>>(bxb, cb, cw, yb);

    // out = y @ Wout^T : M=8192, N=2048, K=2048  (grid 8x32 = 256 blocks)
    gemm_bt8<false><<<dim3(8, 32), 512, 0, stream>>>(
        yb, Woutb, nullptr, nullptr, out, 8192, 2048, 2048);
}